// Round 9
// baseline (236.492 us; speedup 1.0000x reference)
//
#include <hip/hip_runtime.h>

// Problem constants
#define LQ   2048
#define BQ   2
#define HID  1024
#define NH   16
#define DH   64
#define SCALE 0.125f
#define L2E  1.44269504088896f
#define C1   0.18033688011f     // SCALE * log2(e)
#define EXPOFF 23.0831206542f   // 16 * log2(e); fixed softmax max M=16

using short8  = __attribute__((ext_vector_type(8))) short;
using ushort8 = __attribute__((ext_vector_type(8))) unsigned short;
using f32x4   = __attribute__((ext_vector_type(4))) float;
typedef unsigned short u16;
typedef __attribute__((ext_vector_type(2))) __bf16 bf16x2;

__device__ inline u16 f2bf(float x) {
    unsigned int u = __float_as_uint(x);
    u = (u + 0x7fffu + ((u >> 16) & 1u)) >> 16;   // RNE
    return (u16)u;
}

#if defined(__has_builtin)
#if __has_builtin(__builtin_amdgcn_cvt_pk_bf16_f32)
#define HAVE_PKBF 1
#endif
#if __has_builtin(__builtin_amdgcn_exp2f)
#define HAVE_EXP2 1
#endif
#endif

__device__ inline unsigned int pkbf(float a, float b) {
#ifdef HAVE_PKBF
    bf16x2 r = __builtin_amdgcn_cvt_pk_bf16_f32(a, b);
    return __builtin_bit_cast(unsigned int, r);
#else
    return (unsigned int)f2bf(a) | ((unsigned int)f2bf(b) << 16);
#endif
}

__device__ inline float fexp2(float x) {
#ifdef HAVE_EXP2
    return __builtin_amdgcn_exp2f(x);
#else
    return exp2f(x);
#endif
}

// async global->LDS, 16B per lane; LDS dest = wave-uniform base + lane*16
__device__ inline void gl_lds16(const void* g, void* l) {
    __builtin_amdgcn_global_load_lds(
        (const __attribute__((address_space(1))) void*)g,
        (__attribute__((address_space(3))) void*)l, 16, 0, 0);
}

// ---------------------------------------------------------------------------
// castw: cast 7 tensors fp32->bf16 (y=0..6) + mask decode (y==7, x==0).
// ---------------------------------------------------------------------------
struct CastArgs {
    const float* s[7];
    u16* d[7];
    int n[7];
    const unsigned char* mraw;
    int* mout;
    int mn;
};

__global__ __launch_bounds__(256) void castw(CastArgs a) {
    const int y = blockIdx.y;
    const int t = threadIdx.x;
    if (y == 7) {
        if (blockIdx.x != 0) return;
        __shared__ int cnt;
        if (t == 0) cnt = 0;
        __syncthreads();
        int local = 0;
        for (int i = t; i < a.mn; i += 256)
            if ((i & 3) && a.mraw[i]) local++;
        atomicAdd(&cnt, local);
        __syncthreads();
        bool isInt32 = (cnt == 0);
        const int* mi = (const int*)a.mraw;
        for (int i = t; i < a.mn; i += 256)
            a.mout[i] = isInt32 ? mi[i] : (int)a.mraw[i];
        return;
    }
    const float* s = a.s[y];
    u16* d = a.d[y];
    const int n4 = a.n[y] >> 2;
    for (int i = blockIdx.x * 256 + t; i < n4; i += gridDim.x * 256) {
        float4 v = *(const float4*)(s + (size_t)i * 4);
        uint2 p;
        p.x = pkbf(v.x, v.y);
        p.y = pkbf(v.z, v.w);
        *(uint2*)(d + (size_t)i * 4) = p;
    }
}

// ---------------------------------------------------------------------------
// Batched QKV MFMA bf16 GEMM. Tile 128(m input rows) x 64(n = one head), BK=64.
// Grid (32, 16, 3) = 1536 blocks -> 6/CU for drain overlap. LDS 24KB,
// XOR-swizzled (slot c ^ (row&7)), gl_lds16 staging.
// z<2 (Q,K): OPERAND-SWAPPED MFMA (A-op=W, B-op=X): C/D col=lane15=m,
//   reg dir = n = d -> 4 consecutive d pack into one 8B store. [bh][l][d].
// z=2 (V):  unswapped, m-DEINTERLEAVED (m' = b*2048+l; loader remaps rows):
//   reg dir = consecutive l -> 8B packed stores into V^T [bh][d][l].
// Arithmetic identical to R8 (same per-output dot-product order).
// ---------------------------------------------------------------------------
struct QkvArgs {
    const u16* A[3];
    const u16* W[3];
    const float* bias[3];
    u16* out[3];
};

__global__ __launch_bounds__(256) void gemm_qkv(QkvArgs ga) {
    __shared__ u16 Xs[128][64];
    __shared__ u16 Ws[64][64];

    const int z = blockIdx.z;
    const u16* Xg = ga.A[z];
    const u16* Wg = ga.W[z];
    const float* bias = ga.bias[z];
    u16* outp = ga.out[z];

    const int t = threadIdx.x;
    const int m0 = blockIdx.x * 128;
    const int n0 = blockIdx.y * 64;        // one head: h = blockIdx.y
    const int lane = t & 63;
    const int lane15 = lane & 15;
    const int quad = lane >> 4;
    const int w = t >> 6;
    const int mw = (w & 1) * 64;           // wave m-offset within 128
    const int nw = (w >> 1) * 32;          // wave n-offset within 64

    // loader lane mapping (8 rows x 8 chunks per inst)
    const int lrow = lane >> 3;                     // 0..7
    const int ch = (lane & 7) ^ ((lane >> 3) & 7);  // source chunk

    // X row mapping: z<2 direct (g=m), z=2 deinterleaved (m'=b*2048+l -> g=2l+b)
    const int xrow0 = m0 + 32 * w + lrow;           // logical row of inst i base (+8i)
    // W rows: 16w + 8i + lrow over the 64-row W tile
    const u16* wS = Wg + (size_t)(n0 + 16 * w + lrow) * HID + 8 * ch;

    const int s0 = (quad ^ (lane15 & 7)) * 8;
    const int s1 = ((4 + quad) ^ (lane15 & 7)) * 8;

    f32x4 acc[8];   // [ni*4 + mi]
#pragma unroll
    for (int i = 0; i < 8; i++) acc[i] = (f32x4){0,0,0,0};

    // precompute X source pointers for the 4 staging insts
    const u16* xS[4];
#pragma unroll
    for (int i = 0; i < 4; i++) {
        int mrow = xrow0 + 8 * i;                   // logical m (or m')
        int g = (z < 2) ? mrow : (2 * (mrow & 2047) + (mrow >> 11));
        xS[i] = Xg + (size_t)g * HID + 8 * ch;
    }

    for (int k0 = 0; k0 < HID; k0 += 64) {
        __syncthreads();
#pragma unroll
        for (int i = 0; i < 4; i++)
            gl_lds16(xS[i] + k0, &Xs[32 * w + 8 * i][0]);
#pragma unroll
        for (int i = 0; i < 2; i++)
            gl_lds16(wS + (size_t)(8 * i) * HID + k0, &Ws[16 * w + 8 * i][0]);
        __syncthreads();

        short8 xa0[4], xa1[4], wb0[2], wb1[2];
#pragma unroll
        for (int i = 0; i < 4; i++) {
            const u16* xr = &Xs[mw + i * 16 + lane15][0];
            xa0[i] = *(const short8*)(xr + s0);
            xa1[i] = *(const short8*)(xr + s1);
        }
#pragma unroll
        for (int j = 0; j < 2; j++) {
            const u16* wr = &Ws[nw + j * 16 + lane15][0];
            wb0[j] = *(const short8*)(wr + s0);
            wb1[j] = *(const short8*)(wr + s1);
        }
        if (z < 2) {
#pragma unroll
            for (int ni = 0; ni < 2; ni++)
#pragma unroll
                for (int mi = 0; mi < 4; mi++) {
                    acc[ni * 4 + mi] = __builtin_amdgcn_mfma_f32_16x16x32_bf16(wb0[ni], xa0[mi], acc[ni * 4 + mi], 0, 0, 0);
                    acc[ni * 4 + mi] = __builtin_amdgcn_mfma_f32_16x16x32_bf16(wb1[ni], xa1[mi], acc[ni * 4 + mi], 0, 0, 0);
                }
        } else {
#pragma unroll
            for (int ni = 0; ni < 2; ni++)
#pragma unroll
                for (int mi = 0; mi < 4; mi++) {
                    acc[ni * 4 + mi] = __builtin_amdgcn_mfma_f32_16x16x32_bf16(xa0[mi], wb0[ni], acc[ni * 4 + mi], 0, 0, 0);
                    acc[ni * 4 + mi] = __builtin_amdgcn_mfma_f32_16x16x32_bf16(xa1[mi], wb1[ni], acc[ni * 4 + mi], 0, 0, 0);
                }
        }
    }

    const int h = n0 >> 6;
    if (z < 2) {
        // col=lane15 -> m (fixed per lane); regs -> 4 consecutive n (=d)
#pragma unroll
        for (int ni = 0; ni < 2; ni++) {
#pragma unroll
            for (int mi = 0; mi < 4; mi++) {
                const int m = m0 + mw + mi * 16 + lane15;
                const int b = m & 1, l = m >> 1;
                const int d = nw + ni * 16 + quad * 4;
                const f32x4 a = acc[ni * 4 + mi];
                const float4 bv = *(const float4*)&bias[n0 + d];
                uint2 pk2;
                pk2.x = pkbf(a[0] + bv.x, a[1] + bv.y);
                pk2.y = pkbf(a[2] + bv.z, a[3] + bv.w);
                *(uint2*)&outp[(((size_t)(b * NH + h)) * LQ + l) * DH + d] = pk2;
            }
        }
    } else {
        // col=lane15 -> n (=d, fixed); regs -> 4 consecutive m' (= consecutive l)
#pragma unroll
        for (int ni = 0; ni < 2; ni++) {
#pragma unroll
            for (int mi = 0; mi < 4; mi++) {
                const int mp = m0 + mw + mi * 16 + quad * 4;   // m' base
                const int b = mp >> 11;
                const int l = mp & 2047;
                const int d = nw + ni * 16 + lane15;
                const float bv = bias[n0 + d];
                const f32x4 a = acc[ni * 4 + mi];
                uint2 pk2;
                pk2.x = pkbf(a[0] + bv, a[1] + bv);
                pk2.y = pkbf(a[2] + bv, a[3] + bv);
                *(uint2*)&outp[(((size_t)(b * NH + h)) * DH + d) * LQ + l] = pk2;
            }
        }
    }
}

// ---------------------------------------------------------------------------
// FC GEMM (fp32 out), 128x64 tile, BK=64, gl_lds staging, SWAPPED operands:
// col=lane15=m (fixed), regs = 4 consecutive n -> float4 stores.
// ---------------------------------------------------------------------------
__global__ __launch_bounds__(256) void gemm_fc(const u16* __restrict__ A,
                                               const u16* __restrict__ W,
                                               const float* __restrict__ bias,
                                               float* __restrict__ outp) {
    __shared__ u16 As[128][64];
    __shared__ u16 Bs[64][64];

    const int t = threadIdx.x;
    const int m0 = blockIdx.x * 128;
    const int n0 = blockIdx.y * 64;
    const int lane = t & 63;
    const int lane15 = lane & 15;
    const int quad = lane >> 4;
    const int w = t >> 6;
    const int mw = (w & 1) * 64;
    const int nw = (w >> 1) * 32;

    const int lrow = lane >> 3;
    const int ch = (lane & 7) ^ ((lane >> 3) & 7);
    const u16* aS = A + (size_t)(m0 + 32 * w + lrow) * HID + 8 * ch;
    const u16* bS = W + (size_t)(n0 + 16 * w + lrow) * HID + 8 * ch;

    const int s0 = (quad ^ (lane15 & 7)) * 8;
    const int s1 = ((4 + quad) ^ (lane15 & 7)) * 8;

    f32x4 acc[8];
#pragma unroll
    for (int i = 0; i < 8; i++) acc[i] = (f32x4){0,0,0,0};

    for (int k0 = 0; k0 < HID; k0 += 64) {
        __syncthreads();
#pragma unroll
        for (int i = 0; i < 4; i++)
            gl_lds16(aS + (size_t)(8 * i) * HID + k0, &As[32 * w + 8 * i][0]);
#pragma unroll
        for (int i = 0; i < 2; i++)
            gl_lds16(bS + (size_t)(8 * i) * HID + k0, &Bs[16 * w + 8 * i][0]);
        __syncthreads();

        short8 xa0[4], xa1[4], wb0[2], wb1[2];
#pragma unroll
        for (int i = 0; i < 4; i++) {
            const u16* ar = &As[mw + i * 16 + lane15][0];
            xa0[i] = *(const short8*)(ar + s0);
            xa1[i] = *(const short8*)(ar + s1);
        }
#pragma unroll
        for (int j = 0; j < 2; j++) {
            const u16* br = &Bs[nw + j * 16 + lane15][0];
            wb0[j] = *(const short8*)(br + s0);
            wb1[j] = *(const short8*)(br + s1);
        }
#pragma unroll
        for (int ni = 0; ni < 2; ni++)
#pragma unroll
            for (int mi = 0; mi < 4; mi++) {
                acc[ni * 4 + mi] = __builtin_amdgcn_mfma_f32_16x16x32_bf16(wb0[ni], xa0[mi], acc[ni * 4 + mi], 0, 0, 0);
                acc[ni * 4 + mi] = __builtin_amdgcn_mfma_f32_16x16x32_bf16(wb1[ni], xa1[mi], acc[ni * 4 + mi], 0, 0, 0);
            }
    }

#pragma unroll
    for (int ni = 0; ni < 2; ni++) {
#pragma unroll
        for (int mi = 0; mi < 4; mi++) {
            const int m = m0 + mw + mi * 16 + lane15;
            const int n = n0 + nw + ni * 16 + quad * 4;
            const float4 bv = *(const float4*)&bias[n];
            const f32x4 a = acc[ni * 4 + mi];
            float4 o;
            o.x = a[0] + bv.x; o.y = a[1] + bv.y;
            o.z = a[2] + bv.z; o.w = a[3] + bv.w;
            *(float4*)&outp[(size_t)m * HID + n] = o;
        }
    }
}

// ---------------------------------------------------------------------------
// MFMA bf16 flash attention (unchanged from R8).
// ---------------------------------------------------------------------------
#define PSTR 72

__global__ __launch_bounds__(512) void attn_kernel(const u16* __restrict__ Qg,
                                                   const u16* __restrict__ Kg,
                                                   const u16* __restrict__ Vtg,
                                                   const int* __restrict__ maskI,
                                                   const float* __restrict__ tao,
                                                   u16* __restrict__ Xa) {
    __shared__ u16 Ks[128][64];
    __shared__ u16 Vt[64][128];
    __shared__ u16 PT[128][PSTR];
    __shared__ float smask[128];

    const int bh = blockIdx.x;
    const int q0 = blockIdx.y * 128;
    const int b = bh >> 4;
    const int h = bh & 15;
    const int t = threadIdx.x;
    const int w = t >> 6;
    const int lane = t & 63;
    const int lane15 = lane & 15;
    const int quad = lane >> 4;

    const u16* Kbase = Kg + (size_t)bh * LQ * DH;
    const u16* Vtbase = Vtg + (size_t)bh * DH * LQ;
    const int* mrow = maskI + b * LQ;

    const float tv = tao[h];
    const float t2 = tv * tv;
    const float nb = -0.5f / (t2 * t2);
    const float nb2 = nb * L2E;
    const float skipd2 = -40.0f / nb2;

    const int qrow = q0 + w * 16 + lane15;
    short8 qB0, qB1;
    {
        const u16* qp_ = Qg + ((size_t)bh * LQ + qrow) * DH + quad * 8;
        qB0 = *(const short8*)(qp_);
        qB1 = *(const short8*)(qp_ + 32);
    }

    const int krow = 8 * w + (lane >> 3);
    const int kch = (lane & 7) ^ ((lane >> 3) & 7);
    const u16* kS = Kbase + (size_t)krow * DH + 8 * kch;
    const int vrow = 4 * w + (lane >> 4);
    const int vch = (lane & 8) | ((lane & 7) ^ (vrow & 7));
    const u16* vS = Vtbase + (size_t)vrow * LQ + 8 * vch;
    u16* kD0 = &Ks[8 * w][0];
    u16* kD1 = &Ks[64 + 8 * w][0];
    u16* vD0 = &Vt[4 * w][0];
    u16* vD1 = &Vt[32 + 4 * w][0];

    const int s0 = (quad ^ (lane15 & 7)) * 8;
    const int s1 = ((4 + quad) ^ (lane15 & 7)) * 8;

    f32x4 O[4];
#pragma unroll
    for (int mt = 0; mt < 4; mt++) O[mt] = (f32x4){0,0,0,0};
    float l_ = 0.0f;

    const float ebase0 = (float)(qrow - quad * 4);
    const int prow = w * 16 + lane15;

    for (int k0 = 0; k0 < LQ; k0 += 128) {
        {
            int dmin = 0;
            if (k0 > q0 + 127) dmin = k0 - (q0 + 127);
            else if (k0 + 127 < q0) dmin = q0 - (k0 + 127);
            const float df = (float)dmin;
            if (df * df > skipd2) continue;
        }
        __syncthreads();
        gl_lds16(kS + (size_t)k0 * DH, kD0);
        gl_lds16(kS + (size_t)(k0 + 64) * DH, kD1);
        gl_lds16(vS + k0, vD0);
        gl_lds16(vS + (size_t)32 * LQ + k0, vD1);
        if (t < 128) smask[t] = mrow[k0 + t] ? -3.0e38f : -EXPOFF;
        __syncthreads();

#pragma unroll
        for (int hh = 0; hh < 2; hh++) {
            const int kbase = 64 * hh;
            f32x4 S[4];
#pragma unroll
            for (int kt = 0; kt < 4; kt++) {
                const u16* kr = &Ks[kbase + kt * 16 + lane15][0];
                const short8 ka = *(const short8*)(kr + s0);
                const short8 kb = *(const short8*)(kr + s1);
                S[kt] = __builtin_amdgcn_mfma_f32_16x16x32_bf16(ka, qB0, (f32x4){0,0,0,0}, 0, 0, 0);
                S[kt] = __builtin_amdgcn_mfma_f32_16x16x32_bf16(kb, qB1, S[kt], 0, 0, 0);
            }

            const float ebase = ebase0 - (float)(k0 + kbase);
            float lacc = 0.0f;
#pragma unroll
            for (int kt = 0; kt < 4; kt++) {
                const float4 sm4 = *(const float4*)&smask[kbase + kt * 16 + quad * 4];
                float p[4];
#pragma unroll
                for (int r = 0; r < 4; r++) {
                    const float d = ebase - (float)(kt * 16 + r);
                    const float tb = fmaf(nb2 * d, d, ((const float*)&sm4)[r]);
                    p[r] = fexp2(fmaf(S[kt][r], C1, tb));
                    lacc += p[r];
                }
                uint2 pk2;
                pk2.x = pkbf(p[0], p[1]);
                pk2.y = pkbf(p[2], p[3]);
                *(uint2*)&PT[prow][kt * 16 + quad * 4] = pk2;
            }
            l_ += lacc;

            const short8 pB0 = *(const short8*)&PT[prow][quad * 8];
            const short8 pB1 = *(const short8*)&PT[prow][32 + quad * 8];
#pragma unroll
            for (int mt = 0; mt < 4; mt++) {
                const u16* vr = &Vt[mt * 16 + lane15][kbase];
                const short8 va = *(const short8*)(vr + s0);
                const short8 vb = *(const short8*)(vr + s1);
                O[mt] = __builtin_amdgcn_mfma_f32_16x16x32_bf16(va, pB0, O[mt], 0, 0, 0);
                O[mt] = __builtin_amdgcn_mfma_f32_16x16x32_bf16(vb, pB1, O[mt], 0, 0, 0);
            }
        }
    }

    l_ += __shfl_xor(l_, 16, 64);
    l_ += __shfl_xor(l_, 32, 64);

    {
        const float inv = 1.0f / l_;
        u16* dst = Xa + ((size_t)qrow * BQ + b) * HID + h * DH;
#pragma unroll
        for (int mt = 0; mt < 4; mt++) {
            uint2 pk2;
            pk2.x = pkbf(O[mt][0] * inv, O[mt][1] * inv);
            pk2.y = pkbf(O[mt][2] * inv, O[mt][3] * inv);
            *(uint2*)(dst + mt * 16 + quad * 4) = pk2;
        }
    }
}

// ---------------------------------------------------------------------------
extern "C" void kernel_launch(void* const* d_in, const int* in_sizes, int n_in,
                              void* d_out, int out_size, void* d_ws, size_t ws_size,
                              hipStream_t stream) {
    const float* q    = (const float*)d_in[0];
    const float* k    = (const float*)d_in[1];
    const float* v    = (const float*)d_in[2];
    const void*  mask = d_in[3];
    const float* wq   = (const float*)d_in[4];
    const float* wk   = (const float*)d_in[5];
    const float* wv   = (const float*)d_in[6];
    const float* wfc  = (const float*)d_in[7];
    const float* bq   = (const float*)d_in[8];
    const float* bk   = (const float*)d_in[9];
    const float* bv   = (const float*)d_in[10];
    const float* bfc  = (const float*)d_in[11];
    const float* tao  = (const float*)d_in[12];

    const size_t NE = (size_t)LQ * BQ * HID;  // 4,194,304
    const size_t NW = (size_t)HID * HID;      // 1,048,576
    u16* base = (u16*)d_ws;
    u16* Qp    = base;            // [bh][l][d]
    u16* Kp    = base + NE;       // [bh][l][d]
    u16* Vtp   = base + 2 * NE;   // [bh][d][l]
    u16* Xa    = base + 3 * NE;
    u16* qbf   = base + 4 * NE;
    u16* kbf   = base + 5 * NE;
    u16* vbf   = base + 6 * NE;
    u16* wqbf  = base + 7 * NE;
    u16* wkbf  = wqbf + NW;
    u16* wvbf  = wkbf + NW;
    u16* wfcbf = wvbf + NW;
    int* maskI = (int*)(wfcbf + NW);

    CastArgs ca;
    ca.s[0] = q;   ca.d[0] = qbf;   ca.n[0] = (int)NE;
    ca.s[1] = k;   ca.d[1] = kbf;   ca.n[1] = (int)NE;
    ca.s[2] = v;   ca.d[2] = vbf;   ca.n[2] = (int)NE;
    ca.s[3] = wq;  ca.d[3] = wqbf;  ca.n[3] = (int)NW;
    ca.s[4] = wk;  ca.d[4] = wkbf;  ca.n[4] = (int)NW;
    ca.s[5] = wv;  ca.d[5] = wvbf;  ca.n[5] = (int)NW;
    ca.s[6] = wfc; ca.d[6] = wfcbf; ca.n[6] = (int)NW;
    ca.mraw = (const unsigned char*)mask;
    ca.mout = maskI;
    ca.mn = BQ * LQ;
    castw<<<dim3(256, 8), 256, 0, stream>>>(ca);

    QkvArgs ga;
    ga.A[0] = qbf;  ga.W[0] = wqbf;  ga.bias[0] = bq;  ga.out[0] = Qp;
    ga.A[1] = kbf;  ga.W[1] = wkbf;  ga.bias[1] = bk;  ga.out[1] = Kp;
    ga.A[2] = vbf;  ga.W[2] = wvbf;  ga.bias[2] = bv;  ga.out[2] = Vtp;
    gemm_qkv<<<dim3(32, 16, 3), 256, 0, stream>>>(ga);

    attn_kernel<<<dim3(32, 16), 512, 0, stream>>>(Qp, Kp, Vtp, maskI, tao, Xa);

    gemm_fc<<<dim3(32, 16), 256, 0, stream>>>(Xa, wfcbf, bfc, (float*)d_out);
}